// Round 8
// baseline (951.753 us; speedup 1.0000x reference)
//
#include <hip/hip_runtime.h>
#include <stdint.h>

// AttentionBlock: B=8, H*W=4096, C=512; f32 inputs, f32 out (both verified R6).
// R7: m97-style MFMA GEMM. R8/R9: atomic split-K regressed; reverted.
// R10: (P@v)@Wp = P@(v@Wp) + 8-wave 64x128 gemm_bt64. 1153us.
// R11: 2-phase dbuf. 1048us. R12: depth-3 counted-vmcnt pipeline (T4). 952us.
// R13: vectorized norm_partial + Wvp fold (bvp_k serial GEMV cost 87us). 972us.
// R14: parallel bvp + deep-pipe one-time Wvp GEMM. 914us.
// R15: scores GEMM (47.7us x8, MfmaUtil 13%, 2-barrier drain stall) moved to
//     the proven gemm_bt64d deep pipeline: grid (32,64)=2048 blocks, 2/CU.
//     Bit-identical MFMA order -> same Sb. Old 128x128 gemm_bt deleted.

#define BDIM 8
#define SDIM 4096      // H*W
#define CDIM 512
#define SC   2097152   // SDIM*CDIM per-batch elements

typedef unsigned short u16;
typedef __bf16 bf16x8 __attribute__((ext_vector_type(8)));
typedef float  f32x4  __attribute__((ext_vector_type(4)));

__device__ __forceinline__ float b2f(u16 h) {
  union { float f; uint32_t u; } z; z.u = ((uint32_t)h) << 16; return z.f;
}
__device__ __forceinline__ u16 f2b(float f) {
  union { float f; uint32_t u; } z; z.f = f;
  uint32_t u = z.u;
  return (u16)((u + 0x7fffu + ((u >> 16) & 1u)) >> 16);  // RNE
}
__device__ __forceinline__ float sanitize(float v) {
  return fminf(fmaxf(v, -1e4f), 1e4f);
}

// async global->LDS, 16B/lane; LDS dest = wave-uniform base + lane*16
__device__ __forceinline__ void gld_lds16(const u16* g, u16* l) {
  __builtin_amdgcn_global_load_lds(
      (__attribute__((address_space(1))) void*)(uintptr_t)(g),
      (__attribute__((address_space(3))) void*)(uint32_t)(uintptr_t)(l),
      16, 0, 0);
}

// ---------------- input dtype probe (f32 vs bf16) ----------------
__global__ void detect_k(const u16* __restrict__ x, int* __restrict__ flag) {
  int lane = threadIdx.x;                      // 64 lanes
  float v = fabsf(b2f(x[lane * 2]));
  bool huge = !(v < 1e4f);                     // true for NaN too
  unsigned long long m = __ballot(huge);
  if (lane == 0) *flag = (m != 0ull) ? 1 : 0;
}

// ---------------- instance norm (R13: vectorized, 512 blocks) ----------------
// thread t: channel group cg=(t&127) (4 ch), spatial slot sl=t>>7; 64-row chunk
__global__ void norm_partial(const void* __restrict__ xv, const int* __restrict__ flag,
                             float* __restrict__ sums, float* __restrict__ sumsq) {
  bool isf32 = *flag != 0;
  int t = threadIdx.x;
  int cg = t & 127, sl = t >> 7;
  int b = blockIdx.y;
  size_t rowbase = (size_t)b * SDIM + blockIdx.x * 64 + sl;
  float4 s4 = make_float4(0.f, 0.f, 0.f, 0.f);
  float4 q4 = make_float4(0.f, 0.f, 0.f, 0.f);
  if (isf32) {
    const float4* p = (const float4*)xv;       // 128 float4 per spatial row
    #pragma unroll 8
    for (int i = 0; i < 32; ++i) {
      float4 v = p[(rowbase + 2 * i) * 128 + cg];
      s4.x += v.x; s4.y += v.y; s4.z += v.z; s4.w += v.w;
      q4.x += v.x * v.x; q4.y += v.y * v.y; q4.z += v.z * v.z; q4.w += v.w * v.w;
    }
  } else {
    const uint2* p = (const uint2*)xv;         // 4 bf16 per uint2
    #pragma unroll 8
    for (int i = 0; i < 32; ++i) {
      uint2 u = p[(rowbase + 2 * i) * 128 + cg];
      u16* pu = (u16*)&u;
      float v0 = b2f(pu[0]), v1 = b2f(pu[1]), v2 = b2f(pu[2]), v3 = b2f(pu[3]);
      s4.x += v0; s4.y += v1; s4.z += v2; s4.w += v3;
      q4.x += v0 * v0; q4.y += v1 * v1; q4.z += v2 * v2; q4.w += v3 * v3;
    }
  }
  __shared__ float4 rs[128], rq[128];
  if (sl) { rs[cg] = s4; rq[cg] = q4; }
  __syncthreads();
  if (!sl) {
    float4 o = rs[cg], oq = rq[cg];
    float* S = &sums[b * CDIM + cg * 4];
    float* Q = &sumsq[b * CDIM + cg * 4];
    atomicAdd(S + 0, s4.x + o.x);  atomicAdd(S + 1, s4.y + o.y);
    atomicAdd(S + 2, s4.z + o.z);  atomicAdd(S + 3, s4.w + o.w);
    atomicAdd(Q + 0, q4.x + oq.x); atomicAdd(Q + 1, q4.y + oq.y);
    atomicAdd(Q + 2, q4.z + oq.z); atomicAdd(Q + 3, q4.w + oq.w);
  }
}

__global__ void norm_finalize(const float* __restrict__ sums, const float* __restrict__ sumsq,
                              const void* __restrict__ gamma, const void* __restrict__ beta,
                              const int* __restrict__ flag,
                              float* __restrict__ scale, float* __restrict__ shift) {
  bool isf32 = *flag != 0;
  int i = blockIdx.x * 256 + threadIdx.x;      // 4096 = B*C
  int c = i & (CDIM - 1);
  float mean = sums[i] * (1.f / SDIM);
  float var  = sumsq[i] * (1.f / SDIM) - mean * mean;
  float gv = isf32 ? ((const float*)gamma)[c] : b2f(((const u16*)gamma)[c]);
  float bv = isf32 ? ((const float*)beta)[c]  : b2f(((const u16*)beta)[c]);
  float g = gv * rsqrtf(var + 1e-3f);
  scale[i] = g;
  shift[i] = bv - mean * g;
}

// writes f32 xn into d_out (8 elems/thread)
__global__ void normalize_k(const void* __restrict__ xv, const int* __restrict__ flag,
                            const float* __restrict__ scale, const float* __restrict__ shift,
                            float* __restrict__ xn) {
  bool isf32 = *flag != 0;
  int i = blockIdx.x * 256 + threadIdx.x;      // one thread per 8 elements
  int c8 = (i & 63) * 8;
  int b  = i >> 18;
  float in[8];
  if (isf32) {
    float4 f0 = ((const float4*)xv)[(size_t)i * 2];
    float4 f1 = ((const float4*)xv)[(size_t)i * 2 + 1];
    in[0]=f0.x; in[1]=f0.y; in[2]=f0.z; in[3]=f0.w;
    in[4]=f1.x; in[5]=f1.y; in[6]=f1.z; in[7]=f1.w;
  } else {
    uint4 u = ((const uint4*)xv)[i];
    u16* pu = (u16*)&u;
    #pragma unroll
    for (int j = 0; j < 8; ++j) in[j] = b2f(pu[j]);
  }
  const float4* s4 = (const float4*)(scale + b * CDIM + c8);
  const float4* h4 = (const float4*)(shift + b * CDIM + c8);
  float4 sA = s4[0], sB = s4[1], hA = h4[0], hB = h4[1];
  float sc[8] = {sA.x,sA.y,sA.z,sA.w,sB.x,sB.y,sB.z,sB.w};
  float sh[8] = {hA.x,hA.y,hA.z,hA.w,hB.x,hB.y,hB.z,hB.w};
  float4 o0, o1;
  o0.x = in[0]*sc[0]+sh[0]; o0.y = in[1]*sc[1]+sh[1];
  o0.z = in[2]*sc[2]+sh[2]; o0.w = in[3]*sc[3]+sh[3];
  o1.x = in[4]*sc[4]+sh[4]; o1.y = in[5]*sc[5]+sh[5];
  o1.z = in[6]*sc[6]+sh[6]; o1.w = in[7]*sc[7]+sh[7];
  ((float4*)xn)[(size_t)i * 2]     = o0;
  ((float4*)xn)[(size_t)i * 2 + 1] = o1;
}

// ---------------- bias prep (dual dtype) ----------------
__global__ void prep_bias_k(const void* __restrict__ bq, const void* __restrict__ bk,
                            const void* __restrict__ bv, const void* __restrict__ bp,
                            const int* __restrict__ flag,
                            u16* __restrict__ bqkv, u16* __restrict__ bpc) {
  bool isf32 = *flag != 0;
  int i = blockIdx.x * 256 + threadIdx.x;      // 2048
  const void* src; int j; u16* dst; int di;
  if (i < 512)       { src = bq; j = i;        dst = bqkv; di = i; }
  else if (i < 1024) { src = bk; j = i - 512;  dst = bqkv; di = i; }
  else if (i < 1536) { src = bv; j = i - 1024; dst = bqkv; di = i; }   // overwritten by bvp_k
  else               { src = bp; j = i - 1536; dst = bpc;  di = j; }
  dst[di] = isf32 ? f2b(((const float*)src)[j]) : ((const u16*)src)[j];
}

// R14: parallel bvp[c] = sum_k bv[k]*Wp[k][c] -> bqkv[1024+c]
// 8 blocks x 256 thr: block owns 64 cols; thread (c, kslice of 128);
// coalesced Wp row reads; LDS reduce across the 4 k-slices.
__global__ void bvp_k(const void* __restrict__ bv, const void* __restrict__ Wp,
                      const int* __restrict__ flag, u16* __restrict__ bqkv) {
  bool isf32 = *flag != 0;
  int t = threadIdx.x;
  int c = blockIdx.x * 64 + (t & 63);
  int ks = t >> 6;                             // 0..3
  float acc = 0.f;
  #pragma unroll 4
  for (int i = 0; i < 128; ++i) {
    int k = ks * 128 + i;
    float bvk = isf32 ? ((const float*)bv)[k] : b2f(((const u16*)bv)[k]);
    float wkc = isf32 ? ((const float*)Wp)[k * 512 + c] : b2f(((const u16*)Wp)[k * 512 + c]);
    acc += bvk * wkc;
  }
  __shared__ float red[4][64];
  red[ks][t & 63] = acc;
  __syncthreads();
  if (ks == 0)
    bqkv[1024 + c] = f2b(red[0][t & 63] + red[1][t & 63] + red[2][t & 63] + red[3][t & 63]);
}

// raw Wv (dual dtype) -> bf16 linear copy (for the one-time Wvp GEMM)
__global__ void wconv_k(const void* __restrict__ src, u16* __restrict__ dst,
                        const int* __restrict__ flag) {
  bool isf32 = *flag != 0;
  int i = blockIdx.x * 256 + threadIdx.x;      // 32768 threads x 8 elems
  if (isf32) {
    float4 f0 = ((const float4*)src)[(size_t)i * 2];
    float4 f1 = ((const float4*)src)[(size_t)i * 2 + 1];
    union { u16 o[8]; uint4 v; } r;
    r.o[0]=f2b(f0.x); r.o[1]=f2b(f0.y); r.o[2]=f2b(f0.z); r.o[3]=f2b(f0.w);
    r.o[4]=f2b(f1.x); r.o[5]=f2b(f1.y); r.o[6]=f2b(f1.z); r.o[7]=f2b(f1.w);
    ((uint4*)dst)[i] = r.v;
  } else {
    ((uint4*)dst)[i] = ((const uint4*)src)[i];
  }
}

// ---------------- weight transpose 512x512 (input dtype -> bf16) ----------------
__global__ void wtrans_k(const void* __restrict__ src, u16* __restrict__ dst,
                         const int* __restrict__ flag) {
  bool isf32 = *flag != 0;
  __shared__ u16 t[32][33];
  int c0 = blockIdx.x * 32, r0 = blockIdx.y * 32;
  int tx = threadIdx.x & 31, ty = threadIdx.x >> 5;   // 32 x 8
  #pragma unroll
  for (int j = 0; j < 32; j += 8) {
    size_t si = (size_t)(r0 + ty + j) * 512 + c0 + tx;
    t[ty + j][tx] = isf32 ? f2b(((const float*)src)[si]) : ((const u16*)src)[si];
  }
  __syncthreads();
  #pragma unroll
  for (int j = 0; j < 32; j += 8)
    dst[(size_t)(c0 + ty + j) * 512 + r0 + tx] = t[tx][ty + j];
}

// ---------------- fused softmax over rows of 4096 (stats + normalize, one pass)
__global__ void softmax_k(u16* __restrict__ S) {
  int row = blockIdx.x;
  int tid = threadIdx.x, lane = tid & 63, wave = tid >> 6;
  uint4* p = (uint4*)(S + (size_t)row * SDIM);
  uint4 a = p[tid], b = p[256 + tid];          // 16 bf16 per thread, row in regs
  u16* pa = (u16*)&a; u16* pb = (u16*)&b;
  float v[16];
  #pragma unroll
  for (int j = 0; j < 8; ++j) { v[j] = sanitize(b2f(pa[j])); v[8 + j] = sanitize(b2f(pb[j])); }
  float m = v[0];
  #pragma unroll
  for (int j = 1; j < 16; ++j) m = fmaxf(m, v[j]);
  for (int o = 32; o; o >>= 1) m = fmaxf(m, __shfl_xor(m, o));
  __shared__ float red[8];
  if (lane == 0) red[wave] = m;
  __syncthreads();
  m = fmaxf(fmaxf(red[0], red[1]), fmaxf(red[2], red[3]));
  float e[16]; float l = 0.f;
  #pragma unroll
  for (int j = 0; j < 16; ++j) { e[j] = __expf(v[j] - m); l += e[j]; }
  for (int o = 32; o; o >>= 1) l += __shfl_xor(l, o);
  if (lane == 0) red[4 + wave] = l;
  __syncthreads();
  float il = 1.f / (red[4] + red[5] + red[6] + red[7]);
  union { u16 o[8]; uint4 v; } r0, r1;
  #pragma unroll
  for (int j = 0; j < 8; ++j) { r0.o[j] = f2b(e[j] * il); r1.o[j] = f2b(e[8 + j] * il); }
  p[tid] = r0.v;
  p[256 + tid] = r1.v;
}

// ---------------- MFMA GEMM, BM=64 x BN=128, 8 waves, 2-phase dbuf.
// vout: if non-null, cols >= 1024 are stored TRANSPOSED (bf16) to
// vout[(col-1024)*4096 + row] (vWp block of the fused QKV GEMM); cols < 1024
// go to C normally. Branch is block-uniform (tileN multiple of 128).
template <int A_F32, int IO_F32>
__global__ __launch_bounds__(512) void gemm_bt64(
    const void* __restrict__ A, int lda, const u16* __restrict__ Bt, int ldb,
    const u16* __restrict__ bias, const void* __restrict__ resid,
    void* __restrict__ C, int ldc, int M, int N, int K, float alpha,
    u16* __restrict__ vout)
{
  const int tid = threadIdx.x;                 // 512
  const int lane = tid & 63;
  const int wave = tid >> 6;                   // 0..7
  const int wm = wave & 1, wn = wave >> 1;     // 2 x 4
  const int tileM = blockIdx.y * 64, tileN = blockIdx.x * 128;
  const int quad = lane >> 4, l16 = lane & 15;

  __shared__ __align__(16) u16 lsA[2][64 * 64];   // 2 x 8 KB
  __shared__ __align__(16) u16 lsB[2][128 * 64];  // 2 x 16 KB

  f32x4 acc[2][2] = {};

  // A: 512 16B-chunks, 1/thread; B: 1024 chunks, 2/thread
  const int ar = tid >> 3, aq = (tid & 7) ^ (ar & 7);
  int brow[2], bgq[2];
  #pragma unroll
  for (int j = 0; j < 2; ++j) {
    int t = j * 512 + tid;
    brow[j] = t >> 3;
    bgq[j]  = (t & 7) ^ (brow[j] & 7);
  }

  auto stage = [&](int buf, int k0) {
    if (A_F32) {
      const float* src = (const float*)A + (size_t)(tileM + ar) * lda + k0 + aq * 8;
      float4 f0 = ((const float4*)src)[0];
      float4 f1 = ((const float4*)src)[1];
      union { u16 o[8]; uint4 v; } r;
      r.o[0] = f2b(f0.x); r.o[1] = f2b(f0.y); r.o[2] = f2b(f0.z); r.o[3] = f2b(f0.w);
      r.o[4] = f2b(f1.x); r.o[5] = f2b(f1.y); r.o[6] = f2b(f1.z); r.o[7] = f2b(f1.w);
      *(uint4*)&lsA[buf][tid * 8] = r.v;
    } else {
      gld_lds16((const u16*)A + (size_t)(tileM + ar) * lda + k0 + aq * 8,
                &lsA[buf][(wave * 64) * 8]);   // wave-uniform base + lane*16
    }
    #pragma unroll
    for (int j = 0; j < 2; ++j) {
      int lb = (j * 512 + wave * 64) * 8;
      gld_lds16(Bt + (size_t)(tileN + brow[j]) * ldb + k0 + bgq[j] * 8, &lsB[buf][lb]);
    }
  };

  auto compute = [&](int buf) {
    #pragma unroll
    for (int kk8 = 0; kk8 < 8; kk8 += 4) {     // two K=32 MFMA steps
      bf16x8 af[2], bfr[2];
      #pragma unroll
      for (int mi = 0; mi < 2; ++mi) {
        int r = wm * 32 + mi * 16 + l16;
        int slot = (kk8 + quad) ^ (r & 7);
        af[mi] = *(const bf16x8*)&lsA[buf][r * 64 + slot * 8];
      }
      #pragma unroll
      for (int ni = 0; ni < 2; ++ni) {
        int r = wn * 32 + ni * 16 + l16;
        int slot = (kk8 + quad) ^ (r & 7);
        bfr[ni] = *(const bf16x8*)&lsB[buf][r * 64 + slot * 8];
      }
      #pragma unroll
      for (int mi = 0; mi < 2; ++mi)
        #pragma unroll
        for (int ni = 0; ni < 2; ++ni)
          acc[mi][ni] = __builtin_amdgcn_mfma_f32_16x16x32_bf16(af[mi], bfr[ni], acc[mi][ni], 0, 0, 0);
    }
  };

  // prologue: stage tile 0; drain; barrier
  stage(0, 0);
  __syncthreads();
  int cur = 0;
  for (int k0 = 0; k0 + 64 < K; k0 += 64) {
    stage(cur ^ 1, k0 + 64);   // issue next-tile loads (fly under compute)
    compute(cur);
    __syncthreads();           // vmcnt(0)+lgkmcnt(0)+barrier: next buf ready
    cur ^= 1;
  }
  compute(cur);                // last tile, no prefetch

  #pragma unroll
  for (int mi = 0; mi < 2; ++mi) {
    #pragma unroll
    for (int ni = 0; ni < 2; ++ni) {
      f32x4 a = acc[mi][ni];
      int row0 = tileM + wm * 32 + mi * 16 + quad * 4;
      int col  = tileN + wn * 32 + ni * 16 + l16;
      float bv = bias ? b2f(bias[col]) : 0.f;
      if (vout && col >= 1024) {
        // transposed bf16 store: vout[co][row], 4 consecutive rows -> 8B chunk
        union { u16 o[4]; uint2 v; } pk;
        #pragma unroll
        for (int r = 0; r < 4; ++r) pk.o[r] = f2b(a[r] * alpha + bv);
        *(uint2*)&vout[(size_t)(col - 1024) * 4096 + row0] = pk.v;
      } else {
        #pragma unroll
        for (int r = 0; r < 4; ++r) {
          size_t idx = (size_t)(row0 + r) * ldc + col;
          float v = a[r] * alpha + bv;
          if (IO_F32) {
            if (resid) v += ((const float*)resid)[idx];
            ((float*)C)[idx] = v;
          } else {
            if (resid) v += b2f(((const u16*)resid)[idx]);
            ((u16*)C)[idx] = f2b(v);
          }
        }
      }
    }
  }
}

// ---------------- R12: deep-pipelined bf16 GEMM, BM=64 x BN=128, 8 waves.
// Depth-3 LDS buffers + counted vmcnt (T4); raw s_barrier; never vmcnt(0)
// in steady state. R15: also the scores GEMM (2048 blocks, 2/CU at 72KB LDS).
template <int IO_F32>
__global__ __launch_bounds__(512) void gemm_bt64d(
    const u16* __restrict__ A, int lda, const u16* __restrict__ Bt, int ldb,
    const u16* __restrict__ bias, const void* __restrict__ resid,
    void* __restrict__ C, int ldc, int M, int N, int K, float alpha)
{
  const int tid = threadIdx.x;                 // 512
  const int lane = tid & 63;
  const int wave = tid >> 6;                   // 0..7
  const int wm = wave & 1, wn = wave >> 1;     // 2 x 4
  const int tileM = blockIdx.y * 64, tileN = blockIdx.x * 128;
  const int quad = lane >> 4, l16 = lane & 15;

  __shared__ __align__(16) u16 lsA[3][64 * 64];   // 3 x 8 KB
  __shared__ __align__(16) u16 lsB[3][128 * 64];  // 3 x 16 KB

  f32x4 acc[2][2] = {};

  // A: 512 16B-chunks, 1/thread; B: 1024 chunks, 2/thread (3 loads/thread/tile)
  const int ar = tid >> 3, aq = (tid & 7) ^ (ar & 7);
  int brow[2], bgq[2];
  #pragma unroll
  for (int j = 0; j < 2; ++j) {
    int t = j * 512 + tid;
    brow[j] = t >> 3;
    bgq[j]  = (t & 7) ^ (brow[j] & 7);
  }

  auto stage = [&](int buf, int k0) {
    gld_lds16(A + (size_t)(tileM + ar) * lda + k0 + aq * 8,
              &lsA[buf][(wave * 64) * 8]);     // wave-uniform base + lane*16
    #pragma unroll
    for (int j = 0; j < 2; ++j) {
      int lb = (j * 512 + wave * 64) * 8;
      gld_lds16(Bt + (size_t)(tileN + brow[j]) * ldb + k0 + bgq[j] * 8, &lsB[buf][lb]);
    }
  };

  auto compute = [&](int buf) {
    #pragma unroll
    for (int kk8 = 0; kk8 < 8; kk8 += 4) {     // two K=32 MFMA steps
      bf16x8 af[2], bfr[2];
      #pragma unroll
      for (int mi = 0; mi < 2; ++mi) {
        int r = wm * 32 + mi * 16 + l16;
        int slot = (kk8 + quad) ^ (r & 7);
        af[mi] = *(const bf16x8*)&lsA[buf][r * 64 + slot * 8];
      }
      #pragma unroll
      for (int ni = 0; ni < 2; ++ni) {
        int r = wn * 32 + ni * 16 + l16;
        int slot = (kk8 + quad) ^ (r & 7);
        bfr[ni] = *(const bf16x8*)&lsB[buf][r * 64 + slot * 8];
      }
      #pragma unroll
      for (int mi = 0; mi < 2; ++mi)
        #pragma unroll
        for (int ni = 0; ni < 2; ++ni)
          acc[mi][ni] = __builtin_amdgcn_mfma_f32_16x16x32_bf16(af[mi], bfr[ni], acc[mi][ni], 0, 0, 0);
    }
  };

  const int nt = K >> 6;                       // 64-wide K tiles
  // prologue: fill 3 buffers (tail-guarded), wait only tile 0
  stage(0, 0);
  if (nt > 1) stage(1, 64);
  if (nt > 2) stage(2, 128);
  if (nt > 2)      asm volatile("s_waitcnt vmcnt(6)" ::: "memory");
  else if (nt > 1) asm volatile("s_waitcnt vmcnt(3)" ::: "memory");
  else             asm volatile("s_waitcnt vmcnt(0)" ::: "memory");
  __builtin_amdgcn_s_barrier();
  __builtin_amdgcn_sched_barrier(0);

  int cur = 0;
  for (int t = 0; t < nt; ++t) {
    compute(cur);
    asm volatile("s_waitcnt lgkmcnt(0)" ::: "memory");  // my ds_reads retired
    __builtin_amdgcn_s_barrier();              // all waves done reading buf cur
    if (t + 3 < nt) {
      stage(cur, (t + 3) * 64);                // overwrite cur with tile t+3
      asm volatile("s_waitcnt vmcnt(6)" ::: "memory");  // t+1 landed; 6 in flight
    } else if (t + 2 < nt) {
      asm volatile("s_waitcnt vmcnt(3)" ::: "memory");  // t+1 landed; t+2 in flight
    } else {
      asm volatile("s_waitcnt vmcnt(0)" ::: "memory");  // tail drain
    }
    __builtin_amdgcn_s_barrier();              // publish buf (t+1)%3
    __builtin_amdgcn_sched_barrier(0);         // pin ds_reads below barrier
    cur = (cur == 2) ? 0 : cur + 1;
  }

  #pragma unroll
  for (int mi = 0; mi < 2; ++mi) {
    #pragma unroll
    for (int ni = 0; ni < 2; ++ni) {
      f32x4 a = acc[mi][ni];
      int row0 = tileM + wm * 32 + mi * 16 + quad * 4;
      int col  = tileN + wn * 32 + ni * 16 + l16;
      float bv = bias ? b2f(bias[col]) : 0.f;
      #pragma unroll
      for (int r = 0; r < 4; ++r) {
        size_t idx = (size_t)(row0 + r) * ldc + col;
        float v = a[r] * alpha + bv;
        if (IO_F32) {
          if (resid) v += ((const float*)resid)[idx];
          ((float*)C)[idx] = v;
        } else {
          if (resid) v += b2f(((const u16*)resid)[idx]);
          ((u16*)C)[idx] = f2b(v);
        }
      }
    }
  }
}

extern "C" void kernel_launch(void* const* d_in, const int* in_sizes, int n_in,
                              void* d_out, int out_size, void* d_ws, size_t ws_size,
                              hipStream_t stream) {
  const void* x     = d_in[0];
  const void* gamma = d_in[1];
  const void* beta  = d_in[2];
  const void* Wq = d_in[3]; const void* bq = d_in[4];
  const void* Wk = d_in[5]; const void* bk = d_in[6];
  const void* Wv = d_in[7]; const void* bv = d_in[8];
  const void* Wp = d_in[9]; const void* bp = d_in[10];
  float* out = (float*)d_out;                  // f32 output; also the xn buffer

  // ---- workspace layout (16B-aligned offsets) ----
  char* ws = (char*)d_ws;
  float* sums  = (float*)(ws);                 // 16 KB
  float* sumsq = (float*)(ws + 16384);         // 16 KB
  float* scale = (float*)(ws + 32768);         // 16 KB
  float* shift = (float*)(ws + 49152);         // 16 KB
  u16* bqkv    = (u16*)(ws + 98304);           // 3 KB  [bq|bk|bvp]
  u16* bpc     = (u16*)(ws + 102400);          // 1 KB
  int* flag    = (int*)(ws + 110592);          // 4 B
  u16* WqkvT   = (u16*)(ws + 114688);          // [WqT|WkT|WvpT] 1536x512 = 1.5 MB
  u16* WpT     = WqkvT + 786432;               // 512x512  = 0.5 MB
  u16* qkv     = WpT + 262144;                 // 4096x1024 bf16 (q|k) = 8 MB
  u16* vWpT    = qkv + 4194304;                // (v@Wp)^T 512x4096 = 4 MB
  u16* Sb      = vWpT + 2097152;               // RC x 4096 bf16
  const size_t S_off = 14794752;               // byte offset of Sb

  // largest score-chunk rows fitting ws (RC=4096 -> 46.3 MB total)
  int RC = 4096;
  while (RC > 128 && S_off + (size_t)RC * 8192 > ws_size) RC >>= 1;

  // 0) dtype probe
  detect_k<<<1, 64, 0, stream>>>((const u16*)x, flag);

  // 1) instance norm -> f32 xn lives in d_out
  hipMemsetAsync(sums, 0, 32768, stream);      // sums + sumsq
  norm_partial<<<dim3(64, 8), 256, 0, stream>>>(x, flag, sums, sumsq);
  norm_finalize<<<16, 256, 0, stream>>>(sums, sumsq, gamma, beta, flag, scale, shift);
  normalize_k<<<8192, 256, 0, stream>>>(x, flag, scale, shift, out);

  // 2) weight/bias prep
  prep_bias_k<<<8, 256, 0, stream>>>(bq, bk, bv, bp, flag, bqkv, bpc);
  bvp_k<<<8, 256, 0, stream>>>(bv, Wp, flag, bqkv);   // overwrite bqkv[1024..]
  wtrans_k<<<dim3(16, 16), 256, 0, stream>>>(Wq, WqkvT,          flag);
  wtrans_k<<<dim3(16, 16), 256, 0, stream>>>(Wk, WqkvT + 262144, flag);
  wtrans_k<<<dim3(16, 16), 256, 0, stream>>>(Wp, WpT,            flag);
  // Wvp = Wv@Wp folded into QKV weights: WvpT[co][ci] = sum_k WpT[co][k]*Wv[ci][k]
  // Wv_lin staged in vWpT area (dead until first QKV); deep-pipe GEMM (all-bf16).
  wconv_k<<<128, 256, 0, stream>>>(Wv, vWpT, flag);
  gemm_bt64d<0><<<dim3(4, 8), 512, 0, stream>>>(WpT, 512, vWpT, 512,
      nullptr, nullptr, WqkvT + 524288, 512, 512, 512, 512, 1.f);

  const float sscale = 0.0441941738241592f;    // 512^-0.5

  for (int b = 0; b < BDIM; ++b) {
    float* xnb = out + (size_t)b * SC;
    // fused QKVW: (4096x512 f32) @ (512x1536 bf16) -> q|k to qkv (ld 1024),
    // vWp block transposed straight into vWpT. 768 blocks, 8 waves.
    gemm_bt64<1, 0><<<dim3(12, 64), 512, 0, stream>>>(xnb, 512, WqkvT, 512, bqkv,
        nullptr, qkv, 1024, 4096, 1536, 512, 1.f, vWpT);

    for (int rc = 0; rc < SDIM; rc += RC) {
      // scores chunk: q rows rc.. @ k^T (RC x 4096, K=512) -> Sb bf16
      // R15: deep-pipe 64x128 kernel, grid (32, RC/64) -> 2048 blocks, 2/CU
      gemm_bt64d<0><<<dim3(32, RC / 64), 512, 0, stream>>>(qkv + (size_t)rc * 1024, 1024,
          qkv + 512, 1024, nullptr, nullptr, Sb, 4096, RC, 4096, 512, sscale);
      softmax_k<<<RC, 256, 0, stream>>>(Sb);
      // out rows rc.. = P @ (v@Wp) + bp + xn   (RC x 512, K=4096, f32 in-place)
      gemm_bt64d<1><<<dim3(4, RC / 64), 512, 0, stream>>>(Sb, 4096, vWpT, 4096, bpc,
          xnb + (size_t)rc * 512, xnb + (size_t)rc * 512, 512, RC, 512, 4096, 1.f);
    }
  }

  (void)in_sizes; (void)n_in; (void)out_size;
}

// Round 9
// 901.340 us; speedup vs baseline: 1.0559x; 1.0559x over previous
//
#include <hip/hip_runtime.h>
#include <stdint.h>

// AttentionBlock: B=8, H*W=4096, C=512; f32 inputs, f32 out (both verified R6).
// R7: m97-style MFMA GEMM. R8/R9: atomic split-K regressed; reverted.
// R10: (P@v)@Wp = P@(v@Wp) + 8-wave 64x128 gemm_bt64. 1153us.
// R11: 2-phase dbuf. 1048us. R12: depth-3 counted-vmcnt pipeline (T4). 952us.
// R13: vectorized norm_partial + Wvp fold (bvp_k GEMV bug, 972). R14: fixed, 914us.
// R15: scores on 64x128 deep-pipe REGRESSED (951): acc[2][2] halves MFMA per
//     ds_read (1:1 vs 1:2) -> 2x LDS bytes/output; LDS-issue-bound, pipe
//     can't hide that. (fillBufferAligned dispatches = harness re-poison,
//     outside dur_us — ignore.)
// R16: gemm_bt256d — BM=128 x BN=256, 8 waves, acc[4][4] (0.5 read/MFMA, the
//     good intensity) + depth-3 counted vmcnt(12). LDS 144KB, 1 blk/CU,
//     scores grid (16,32)=512 blocks. Same K-order -> bit-identical Sb.

#define BDIM 8
#define SDIM 4096      // H*W
#define CDIM 512
#define SC   2097152   // SDIM*CDIM per-batch elements

typedef unsigned short u16;
typedef __bf16 bf16x8 __attribute__((ext_vector_type(8)));
typedef float  f32x4  __attribute__((ext_vector_type(4)));

__device__ __forceinline__ float b2f(u16 h) {
  union { float f; uint32_t u; } z; z.u = ((uint32_t)h) << 16; return z.f;
}
__device__ __forceinline__ u16 f2b(float f) {
  union { float f; uint32_t u; } z; z.f = f;
  uint32_t u = z.u;
  return (u16)((u + 0x7fffu + ((u >> 16) & 1u)) >> 16);  // RNE
}
__device__ __forceinline__ float sanitize(float v) {
  return fminf(fmaxf(v, -1e4f), 1e4f);
}

// async global->LDS, 16B/lane; LDS dest = wave-uniform base + lane*16
__device__ __forceinline__ void gld_lds16(const u16* g, u16* l) {
  __builtin_amdgcn_global_load_lds(
      (__attribute__((address_space(1))) void*)(uintptr_t)(g),
      (__attribute__((address_space(3))) void*)(uint32_t)(uintptr_t)(l),
      16, 0, 0);
}

// ---------------- input dtype probe (f32 vs bf16) ----------------
__global__ void detect_k(const u16* __restrict__ x, int* __restrict__ flag) {
  int lane = threadIdx.x;                      // 64 lanes
  float v = fabsf(b2f(x[lane * 2]));
  bool huge = !(v < 1e4f);                     // true for NaN too
  unsigned long long m = __ballot(huge);
  if (lane == 0) *flag = (m != 0ull) ? 1 : 0;
}

// ---------------- instance norm (R13: vectorized, 512 blocks) ----------------
__global__ void norm_partial(const void* __restrict__ xv, const int* __restrict__ flag,
                             float* __restrict__ sums, float* __restrict__ sumsq) {
  bool isf32 = *flag != 0;
  int t = threadIdx.x;
  int cg = t & 127, sl = t >> 7;
  int b = blockIdx.y;
  size_t rowbase = (size_t)b * SDIM + blockIdx.x * 64 + sl;
  float4 s4 = make_float4(0.f, 0.f, 0.f, 0.f);
  float4 q4 = make_float4(0.f, 0.f, 0.f, 0.f);
  if (isf32) {
    const float4* p = (const float4*)xv;       // 128 float4 per spatial row
    #pragma unroll 8
    for (int i = 0; i < 32; ++i) {
      float4 v = p[(rowbase + 2 * i) * 128 + cg];
      s4.x += v.x; s4.y += v.y; s4.z += v.z; s4.w += v.w;
      q4.x += v.x * v.x; q4.y += v.y * v.y; q4.z += v.z * v.z; q4.w += v.w * v.w;
    }
  } else {
    const uint2* p = (const uint2*)xv;         // 4 bf16 per uint2
    #pragma unroll 8
    for (int i = 0; i < 32; ++i) {
      uint2 u = p[(rowbase + 2 * i) * 128 + cg];
      u16* pu = (u16*)&u;
      float v0 = b2f(pu[0]), v1 = b2f(pu[1]), v2 = b2f(pu[2]), v3 = b2f(pu[3]);
      s4.x += v0; s4.y += v1; s4.z += v2; s4.w += v3;
      q4.x += v0 * v0; q4.y += v1 * v1; q4.z += v2 * v2; q4.w += v3 * v3;
    }
  }
  __shared__ float4 rs[128], rq[128];
  if (sl) { rs[cg] = s4; rq[cg] = q4; }
  __syncthreads();
  if (!sl) {
    float4 o = rs[cg], oq = rq[cg];
    float* S = &sums[b * CDIM + cg * 4];
    float* Q = &sumsq[b * CDIM + cg * 4];
    atomicAdd(S + 0, s4.x + o.x);  atomicAdd(S + 1, s4.y + o.y);
    atomicAdd(S + 2, s4.z + o.z);  atomicAdd(S + 3, s4.w + o.w);
    atomicAdd(Q + 0, q4.x + oq.x); atomicAdd(Q + 1, q4.y + oq.y);
    atomicAdd(Q + 2, q4.z + oq.z); atomicAdd(Q + 3, q4.w + oq.w);
  }
}

__global__ void norm_finalize(const float* __restrict__ sums, const float* __restrict__ sumsq,
                              const void* __restrict__ gamma, const void* __restrict__ beta,
                              const int* __restrict__ flag,
                              float* __restrict__ scale, float* __restrict__ shift) {
  bool isf32 = *flag != 0;
  int i = blockIdx.x * 256 + threadIdx.x;      // 4096 = B*C
  int c = i & (CDIM - 1);
  float mean = sums[i] * (1.f / SDIM);
  float var  = sumsq[i] * (1.f / SDIM) - mean * mean;
  float gv = isf32 ? ((const float*)gamma)[c] : b2f(((const u16*)gamma)[c]);
  float bv = isf32 ? ((const float*)beta)[c]  : b2f(((const u16*)beta)[c]);
  float g = gv * rsqrtf(var + 1e-3f);
  scale[i] = g;
  shift[i] = bv - mean * g;
}

// writes f32 xn into d_out (8 elems/thread)
__global__ void normalize_k(const void* __restrict__ xv, const int* __restrict__ flag,
                            const float* __restrict__ scale, const float* __restrict__ shift,
                            float* __restrict__ xn) {
  bool isf32 = *flag != 0;
  int i = blockIdx.x * 256 + threadIdx.x;      // one thread per 8 elements
  int c8 = (i & 63) * 8;
  int b  = i >> 18;
  float in[8];
  if (isf32) {
    float4 f0 = ((const float4*)xv)[(size_t)i * 2];
    float4 f1 = ((const float4*)xv)[(size_t)i * 2 + 1];
    in[0]=f0.x; in[1]=f0.y; in[2]=f0.z; in[3]=f0.w;
    in[4]=f1.x; in[5]=f1.y; in[6]=f1.z; in[7]=f1.w;
  } else {
    uint4 u = ((const uint4*)xv)[i];
    u16* pu = (u16*)&u;
    #pragma unroll
    for (int j = 0; j < 8; ++j) in[j] = b2f(pu[j]);
  }
  const float4* s4 = (const float4*)(scale + b * CDIM + c8);
  const float4* h4 = (const float4*)(shift + b * CDIM + c8);
  float4 sA = s4[0], sB = s4[1], hA = h4[0], hB = h4[1];
  float sc[8] = {sA.x,sA.y,sA.z,sA.w,sB.x,sB.y,sB.z,sB.w};
  float sh[8] = {hA.x,hA.y,hA.z,hA.w,hB.x,hB.y,hB.z,hB.w};
  float4 o0, o1;
  o0.x = in[0]*sc[0]+sh[0]; o0.y = in[1]*sc[1]+sh[1];
  o0.z = in[2]*sc[2]+sh[2]; o0.w = in[3]*sc[3]+sh[3];
  o1.x = in[4]*sc[4]+sh[4]; o1.y = in[5]*sc[5]+sh[5];
  o1.z = in[6]*sc[6]+sh[6]; o1.w = in[7]*sc[7]+sh[7];
  ((float4*)xn)[(size_t)i * 2]     = o0;
  ((float4*)xn)[(size_t)i * 2 + 1] = o1;
}

// ---------------- bias prep (dual dtype) ----------------
__global__ void prep_bias_k(const void* __restrict__ bq, const void* __restrict__ bk,
                            const void* __restrict__ bv, const void* __restrict__ bp,
                            const int* __restrict__ flag,
                            u16* __restrict__ bqkv, u16* __restrict__ bpc) {
  bool isf32 = *flag != 0;
  int i = blockIdx.x * 256 + threadIdx.x;      // 2048
  const void* src; int j; u16* dst; int di;
  if (i < 512)       { src = bq; j = i;        dst = bqkv; di = i; }
  else if (i < 1024) { src = bk; j = i - 512;  dst = bqkv; di = i; }
  else if (i < 1536) { src = bv; j = i - 1024; dst = bqkv; di = i; }   // overwritten by bvp_k
  else               { src = bp; j = i - 1536; dst = bpc;  di = j; }
  dst[di] = isf32 ? f2b(((const float*)src)[j]) : ((const u16*)src)[j];
}

// R14: parallel bvp[c] = sum_k bv[k]*Wp[k][c] -> bqkv[1024+c]
__global__ void bvp_k(const void* __restrict__ bv, const void* __restrict__ Wp,
                      const int* __restrict__ flag, u16* __restrict__ bqkv) {
  bool isf32 = *flag != 0;
  int t = threadIdx.x;
  int c = blockIdx.x * 64 + (t & 63);
  int ks = t >> 6;                             // 0..3
  float acc = 0.f;
  #pragma unroll 4
  for (int i = 0; i < 128; ++i) {
    int k = ks * 128 + i;
    float bvk = isf32 ? ((const float*)bv)[k] : b2f(((const u16*)bv)[k]);
    float wkc = isf32 ? ((const float*)Wp)[k * 512 + c] : b2f(((const u16*)Wp)[k * 512 + c]);
    acc += bvk * wkc;
  }
  __shared__ float red[4][64];
  red[ks][t & 63] = acc;
  __syncthreads();
  if (ks == 0)
    bqkv[1024 + c] = f2b(red[0][t & 63] + red[1][t & 63] + red[2][t & 63] + red[3][t & 63]);
}

// raw Wv (dual dtype) -> bf16 linear copy (for the one-time Wvp GEMM)
__global__ void wconv_k(const void* __restrict__ src, u16* __restrict__ dst,
                        const int* __restrict__ flag) {
  bool isf32 = *flag != 0;
  int i = blockIdx.x * 256 + threadIdx.x;      // 32768 threads x 8 elems
  if (isf32) {
    float4 f0 = ((const float4*)src)[(size_t)i * 2];
    float4 f1 = ((const float4*)src)[(size_t)i * 2 + 1];
    union { u16 o[8]; uint4 v; } r;
    r.o[0]=f2b(f0.x); r.o[1]=f2b(f0.y); r.o[2]=f2b(f0.z); r.o[3]=f2b(f0.w);
    r.o[4]=f2b(f1.x); r.o[5]=f2b(f1.y); r.o[6]=f2b(f1.z); r.o[7]=f2b(f1.w);
    ((uint4*)dst)[i] = r.v;
  } else {
    ((uint4*)dst)[i] = ((const uint4*)src)[i];
  }
}

// ---------------- weight transpose 512x512 (input dtype -> bf16) ----------------
__global__ void wtrans_k(const void* __restrict__ src, u16* __restrict__ dst,
                         const int* __restrict__ flag) {
  bool isf32 = *flag != 0;
  __shared__ u16 t[32][33];
  int c0 = blockIdx.x * 32, r0 = blockIdx.y * 32;
  int tx = threadIdx.x & 31, ty = threadIdx.x >> 5;   // 32 x 8
  #pragma unroll
  for (int j = 0; j < 32; j += 8) {
    size_t si = (size_t)(r0 + ty + j) * 512 + c0 + tx;
    t[ty + j][tx] = isf32 ? f2b(((const float*)src)[si]) : ((const u16*)src)[si];
  }
  __syncthreads();
  #pragma unroll
  for (int j = 0; j < 32; j += 8)
    dst[(size_t)(c0 + ty + j) * 512 + r0 + tx] = t[tx][ty + j];
}

// ---------------- fused softmax over rows of 4096 (stats + normalize, one pass)
__global__ void softmax_k(u16* __restrict__ S) {
  int row = blockIdx.x;
  int tid = threadIdx.x, lane = tid & 63, wave = tid >> 6;
  uint4* p = (uint4*)(S + (size_t)row * SDIM);
  uint4 a = p[tid], b = p[256 + tid];          // 16 bf16 per thread, row in regs
  u16* pa = (u16*)&a; u16* pb = (u16*)&b;
  float v[16];
  #pragma unroll
  for (int j = 0; j < 8; ++j) { v[j] = sanitize(b2f(pa[j])); v[8 + j] = sanitize(b2f(pb[j])); }
  float m = v[0];
  #pragma unroll
  for (int j = 1; j < 16; ++j) m = fmaxf(m, v[j]);
  for (int o = 32; o; o >>= 1) m = fmaxf(m, __shfl_xor(m, o));
  __shared__ float red[8];
  if (lane == 0) red[wave] = m;
  __syncthreads();
  m = fmaxf(fmaxf(red[0], red[1]), fmaxf(red[2], red[3]));
  float e[16]; float l = 0.f;
  #pragma unroll
  for (int j = 0; j < 16; ++j) { e[j] = __expf(v[j] - m); l += e[j]; }
  for (int o = 32; o; o >>= 1) l += __shfl_xor(l, o);
  if (lane == 0) red[4 + wave] = l;
  __syncthreads();
  float il = 1.f / (red[4] + red[5] + red[6] + red[7]);
  union { u16 o[8]; uint4 v; } r0, r1;
  #pragma unroll
  for (int j = 0; j < 8; ++j) { r0.o[j] = f2b(e[j] * il); r1.o[j] = f2b(e[8 + j] * il); }
  p[tid] = r0.v;
  p[256 + tid] = r1.v;
}

// ---------------- MFMA GEMM, BM=64 x BN=128, 8 waves, 2-phase dbuf.
// vout: if non-null, cols >= 1024 are stored TRANSPOSED (bf16) to
// vout[(col-1024)*4096 + row]. Branch is block-uniform (tileN mult of 128).
template <int A_F32, int IO_F32>
__global__ __launch_bounds__(512) void gemm_bt64(
    const void* __restrict__ A, int lda, const u16* __restrict__ Bt, int ldb,
    const u16* __restrict__ bias, const void* __restrict__ resid,
    void* __restrict__ C, int ldc, int M, int N, int K, float alpha,
    u16* __restrict__ vout)
{
  const int tid = threadIdx.x;                 // 512
  const int lane = tid & 63;
  const int wave = tid >> 6;                   // 0..7
  const int wm = wave & 1, wn = wave >> 1;     // 2 x 4
  const int tileM = blockIdx.y * 64, tileN = blockIdx.x * 128;
  const int quad = lane >> 4, l16 = lane & 15;

  __shared__ __align__(16) u16 lsA[2][64 * 64];   // 2 x 8 KB
  __shared__ __align__(16) u16 lsB[2][128 * 64];  // 2 x 16 KB

  f32x4 acc[2][2] = {};

  const int ar = tid >> 3, aq = (tid & 7) ^ (ar & 7);
  int brow[2], bgq[2];
  #pragma unroll
  for (int j = 0; j < 2; ++j) {
    int t = j * 512 + tid;
    brow[j] = t >> 3;
    bgq[j]  = (t & 7) ^ (brow[j] & 7);
  }

  auto stage = [&](int buf, int k0) {
    if (A_F32) {
      const float* src = (const float*)A + (size_t)(tileM + ar) * lda + k0 + aq * 8;
      float4 f0 = ((const float4*)src)[0];
      float4 f1 = ((const float4*)src)[1];
      union { u16 o[8]; uint4 v; } r;
      r.o[0] = f2b(f0.x); r.o[1] = f2b(f0.y); r.o[2] = f2b(f0.z); r.o[3] = f2b(f0.w);
      r.o[4] = f2b(f1.x); r.o[5] = f2b(f1.y); r.o[6] = f2b(f1.z); r.o[7] = f2b(f1.w);
      *(uint4*)&lsA[buf][tid * 8] = r.v;
    } else {
      gld_lds16((const u16*)A + (size_t)(tileM + ar) * lda + k0 + aq * 8,
                &lsA[buf][(wave * 64) * 8]);   // wave-uniform base + lane*16
    }
    #pragma unroll
    for (int j = 0; j < 2; ++j) {
      int lb = (j * 512 + wave * 64) * 8;
      gld_lds16(Bt + (size_t)(tileN + brow[j]) * ldb + k0 + bgq[j] * 8, &lsB[buf][lb]);
    }
  };

  auto compute = [&](int buf) {
    #pragma unroll
    for (int kk8 = 0; kk8 < 8; kk8 += 4) {     // two K=32 MFMA steps
      bf16x8 af[2], bfr[2];
      #pragma unroll
      for (int mi = 0; mi < 2; ++mi) {
        int r = wm * 32 + mi * 16 + l16;
        int slot = (kk8 + quad) ^ (r & 7);
        af[mi] = *(const bf16x8*)&lsA[buf][r * 64 + slot * 8];
      }
      #pragma unroll
      for (int ni = 0; ni < 2; ++ni) {
        int r = wn * 32 + ni * 16 + l16;
        int slot = (kk8 + quad) ^ (r & 7);
        bfr[ni] = *(const bf16x8*)&lsB[buf][r * 64 + slot * 8];
      }
      #pragma unroll
      for (int mi = 0; mi < 2; ++mi)
        #pragma unroll
        for (int ni = 0; ni < 2; ++ni)
          acc[mi][ni] = __builtin_amdgcn_mfma_f32_16x16x32_bf16(af[mi], bfr[ni], acc[mi][ni], 0, 0, 0);
    }
  };

  stage(0, 0);
  __syncthreads();
  int cur = 0;
  for (int k0 = 0; k0 + 64 < K; k0 += 64) {
    stage(cur ^ 1, k0 + 64);
    compute(cur);
    __syncthreads();
    cur ^= 1;
  }
  compute(cur);

  #pragma unroll
  for (int mi = 0; mi < 2; ++mi) {
    #pragma unroll
    for (int ni = 0; ni < 2; ++ni) {
      f32x4 a = acc[mi][ni];
      int row0 = tileM + wm * 32 + mi * 16 + quad * 4;
      int col  = tileN + wn * 32 + ni * 16 + l16;
      float bv = bias ? b2f(bias[col]) : 0.f;
      if (vout && col >= 1024) {
        union { u16 o[4]; uint2 v; } pk;
        #pragma unroll
        for (int r = 0; r < 4; ++r) pk.o[r] = f2b(a[r] * alpha + bv);
        *(uint2*)&vout[(size_t)(col - 1024) * 4096 + row0] = pk.v;
      } else {
        #pragma unroll
        for (int r = 0; r < 4; ++r) {
          size_t idx = (size_t)(row0 + r) * ldc + col;
          float v = a[r] * alpha + bv;
          if (IO_F32) {
            if (resid) v += ((const float*)resid)[idx];
            ((float*)C)[idx] = v;
          } else {
            if (resid) v += b2f(((const u16*)resid)[idx]);
            ((u16*)C)[idx] = f2b(v);
          }
        }
      }
    }
  }
}

// ---------------- R12: deep-pipelined bf16 GEMM, BM=64 x BN=128, 8 waves.
// Depth-3 LDS buffers + counted vmcnt (T4). Used by PV' (256 blocks) and the
// one-time Wvp GEMM. 3 loads/thread/stage -> vmcnt(6)/(3)/(0).
template <int IO_F32>
__global__ __launch_bounds__(512) void gemm_bt64d(
    const u16* __restrict__ A, int lda, const u16* __restrict__ Bt, int ldb,
    const u16* __restrict__ bias, const void* __restrict__ resid,
    void* __restrict__ C, int ldc, int M, int N, int K, float alpha)
{
  const int tid = threadIdx.x;                 // 512
  const int lane = tid & 63;
  const int wave = tid >> 6;                   // 0..7
  const int wm = wave & 1, wn = wave >> 1;     // 2 x 4
  const int tileM = blockIdx.y * 64, tileN = blockIdx.x * 128;
  const int quad = lane >> 4, l16 = lane & 15;

  __shared__ __align__(16) u16 lsA[3][64 * 64];   // 3 x 8 KB
  __shared__ __align__(16) u16 lsB[3][128 * 64];  // 3 x 16 KB

  f32x4 acc[2][2] = {};

  const int ar = tid >> 3, aq = (tid & 7) ^ (ar & 7);
  int brow[2], bgq[2];
  #pragma unroll
  for (int j = 0; j < 2; ++j) {
    int t = j * 512 + tid;
    brow[j] = t >> 3;
    bgq[j]  = (t & 7) ^ (brow[j] & 7);
  }

  auto stage = [&](int buf, int k0) {
    gld_lds16(A + (size_t)(tileM + ar) * lda + k0 + aq * 8,
              &lsA[buf][(wave * 64) * 8]);
    #pragma unroll
    for (int j = 0; j < 2; ++j) {
      int lb = (j * 512 + wave * 64) * 8;
      gld_lds16(Bt + (size_t)(tileN + brow[j]) * ldb + k0 + bgq[j] * 8, &lsB[buf][lb]);
    }
  };

  auto compute = [&](int buf) {
    #pragma unroll
    for (int kk8 = 0; kk8 < 8; kk8 += 4) {
      bf16x8 af[2], bfr[2];
      #pragma unroll
      for (int mi = 0; mi < 2; ++mi) {
        int r = wm * 32 + mi * 16 + l16;
        int slot = (kk8 + quad) ^ (r & 7);
        af[mi] = *(const bf16x8*)&lsA[buf][r * 64 + slot * 8];
      }
      #pragma unroll
      for (int ni = 0; ni < 2; ++ni) {
        int r = wn * 32 + ni * 16 + l16;
        int slot = (kk8 + quad) ^ (r & 7);
        bfr[ni] = *(const bf16x8*)&lsB[buf][r * 64 + slot * 8];
      }
      #pragma unroll
      for (int mi = 0; mi < 2; ++mi)
        #pragma unroll
        for (int ni = 0; ni < 2; ++ni)
          acc[mi][ni] = __builtin_amdgcn_mfma_f32_16x16x32_bf16(af[mi], bfr[ni], acc[mi][ni], 0, 0, 0);
    }
  };

  const int nt = K >> 6;
  stage(0, 0);
  if (nt > 1) stage(1, 64);
  if (nt > 2) stage(2, 128);
  if (nt > 2)      asm volatile("s_waitcnt vmcnt(6)" ::: "memory");
  else if (nt > 1) asm volatile("s_waitcnt vmcnt(3)" ::: "memory");
  else             asm volatile("s_waitcnt vmcnt(0)" ::: "memory");
  __builtin_amdgcn_s_barrier();
  __builtin_amdgcn_sched_barrier(0);

  int cur = 0;
  for (int t = 0; t < nt; ++t) {
    compute(cur);
    asm volatile("s_waitcnt lgkmcnt(0)" ::: "memory");
    __builtin_amdgcn_s_barrier();
    if (t + 3 < nt) {
      stage(cur, (t + 3) * 64);
      asm volatile("s_waitcnt vmcnt(6)" ::: "memory");
    } else if (t + 2 < nt) {
      asm volatile("s_waitcnt vmcnt(3)" ::: "memory");
    } else {
      asm volatile("s_waitcnt vmcnt(0)" ::: "memory");
    }
    __builtin_amdgcn_s_barrier();
    __builtin_amdgcn_sched_barrier(0);
    cur = (cur == 2) ? 0 : cur + 1;
  }

  #pragma unroll
  for (int mi = 0; mi < 2; ++mi) {
    #pragma unroll
    for (int ni = 0; ni < 2; ++ni) {
      f32x4 a = acc[mi][ni];
      int row0 = tileM + wm * 32 + mi * 16 + quad * 4;
      int col  = tileN + wn * 32 + ni * 16 + l16;
      float bv = bias ? b2f(bias[col]) : 0.f;
      #pragma unroll
      for (int r = 0; r < 4; ++r) {
        size_t idx = (size_t)(row0 + r) * ldc + col;
        float v = a[r] * alpha + bv;
        if (IO_F32) {
          if (resid) v += ((const float*)resid)[idx];
          ((float*)C)[idx] = v;
        } else {
          if (resid) v += b2f(((const u16*)resid)[idx]);
          ((u16*)C)[idx] = f2b(v);
        }
      }
    }
  }
}

// ---------------- R16: deep-pipelined bf16 GEMM, BM=128 x BN=256, 8 waves.
// Wave = 64x64 sub-tile, acc[4][4] (0.5 ds_read per MFMA). LDS 3x48=144KB,
// 1 block/CU. 6 loads/thread/stage -> counted vmcnt(12)/(6)/(0).
// For the scores GEMM: grid (N/256, M/128) = (16, 32) = 512 blocks.
template <int IO_F32>
__global__ __launch_bounds__(512) void gemm_bt256d(
    const u16* __restrict__ A, int lda, const u16* __restrict__ Bt, int ldb,
    const u16* __restrict__ bias, const void* __restrict__ resid,
    void* __restrict__ C, int ldc, int M, int N, int K, float alpha)
{
  const int tid = threadIdx.x;                 // 512
  const int lane = tid & 63;
  const int wave = tid >> 6;                   // 0..7
  const int wm = wave & 1, wn = wave >> 1;     // 2 x 4
  const int tileM = blockIdx.y * 128, tileN = blockIdx.x * 256;
  const int quad = lane >> 4, l16 = lane & 15;

  __shared__ __align__(16) u16 lsA[3][128 * 64];  // 3 x 16 KB
  __shared__ __align__(16) u16 lsB[3][256 * 64];  // 3 x 32 KB

  f32x4 acc[4][4] = {};

  // A: 1024 16B-chunks, 2/thread; B: 2048 chunks, 4/thread
  int arow[2], agq[2];
  #pragma unroll
  for (int j = 0; j < 2; ++j) {
    int t = j * 512 + tid;
    arow[j] = t >> 3;
    agq[j]  = (t & 7) ^ (arow[j] & 7);
  }
  int brow[4], bgq[4];
  #pragma unroll
  for (int j = 0; j < 4; ++j) {
    int t = j * 512 + tid;
    brow[j] = t >> 3;
    bgq[j]  = (t & 7) ^ (brow[j] & 7);
  }

  auto stage = [&](int buf, int k0) {
    #pragma unroll
    for (int j = 0; j < 2; ++j) {
      int lb = (j * 512 + wave * 64) * 8;
      gld_lds16(A + (size_t)(tileM + arow[j]) * lda + k0 + agq[j] * 8, &lsA[buf][lb]);
    }
    #pragma unroll
    for (int j = 0; j < 4; ++j) {
      int lb = (j * 512 + wave * 64) * 8;
      gld_lds16(Bt + (size_t)(tileN + brow[j]) * ldb + k0 + bgq[j] * 8, &lsB[buf][lb]);
    }
  };

  auto compute = [&](int buf) {
    #pragma unroll
    for (int kk8 = 0; kk8 < 8; kk8 += 4) {     // two K=32 MFMA steps
      bf16x8 af[4], bfr[4];
      #pragma unroll
      for (int mi = 0; mi < 4; ++mi) {
        int r = wm * 64 + mi * 16 + l16;
        int slot = (kk8 + quad) ^ (r & 7);
        af[mi] = *(const bf16x8*)&lsA[buf][r * 64 + slot * 8];
      }
      #pragma unroll
      for (int ni = 0; ni < 4; ++ni) {
        int r = wn * 64 + ni * 16 + l16;
        int slot = (kk8 + quad) ^ (r & 7);
        bfr[ni] = *(const bf16x8*)&lsB[buf][r * 64 + slot * 8];
      }
      #pragma unroll
      for (int mi = 0; mi < 4; ++mi)
        #pragma unroll
        for (int ni = 0; ni < 4; ++ni)
          acc[mi][ni] = __builtin_amdgcn_mfma_f32_16x16x32_bf16(af[mi], bfr[ni], acc[mi][ni], 0, 0, 0);
    }
  };

  const int nt = K >> 6;
  stage(0, 0);
  if (nt > 1) stage(1, 64);
  if (nt > 2) stage(2, 128);
  if (nt > 2)      asm volatile("s_waitcnt vmcnt(12)" ::: "memory");
  else if (nt > 1) asm volatile("s_waitcnt vmcnt(6)" ::: "memory");
  else             asm volatile("s_waitcnt vmcnt(0)" ::: "memory");
  __builtin_amdgcn_s_barrier();
  __builtin_amdgcn_sched_barrier(0);

  int cur = 0;
  for (int t = 0; t < nt; ++t) {
    compute(cur);
    asm volatile("s_waitcnt lgkmcnt(0)" ::: "memory");
    __builtin_amdgcn_s_barrier();
    if (t + 3 < nt) {
      stage(cur, (t + 3) * 64);
      asm volatile("s_waitcnt vmcnt(12)" ::: "memory"); // t+1 landed; 12 in flight
    } else if (t + 2 < nt) {
      asm volatile("s_waitcnt vmcnt(6)" ::: "memory");  // t+1 landed; t+2 in flight
    } else {
      asm volatile("s_waitcnt vmcnt(0)" ::: "memory");  // tail drain
    }
    __builtin_amdgcn_s_barrier();
    __builtin_amdgcn_sched_barrier(0);
    cur = (cur == 2) ? 0 : cur + 1;
  }

  #pragma unroll
  for (int mi = 0; mi < 4; ++mi) {
    #pragma unroll
    for (int ni = 0; ni < 4; ++ni) {
      f32x4 a = acc[mi][ni];
      int row0 = tileM + wm * 64 + mi * 16 + quad * 4;
      int col  = tileN + wn * 64 + ni * 16 + l16;
      float bv = bias ? b2f(bias[col]) : 0.f;
      #pragma unroll
      for (int r = 0; r < 4; ++r) {
        size_t idx = (size_t)(row0 + r) * ldc + col;
        float v = a[r] * alpha + bv;
        if (IO_F32) {
          if (resid) v += ((const float*)resid)[idx];
          ((float*)C)[idx] = v;
        } else {
          if (resid) v += b2f(((const u16*)resid)[idx]);
          ((u16*)C)[idx] = f2b(v);
        }
      }
    }
  }
}

extern "C" void kernel_launch(void* const* d_in, const int* in_sizes, int n_in,
                              void* d_out, int out_size, void* d_ws, size_t ws_size,
                              hipStream_t stream) {
  const void* x     = d_in[0];
  const void* gamma = d_in[1];
  const void* beta  = d_in[2];
  const void* Wq = d_in[3]; const void* bq = d_in[4];
  const void* Wk = d_in[5]; const void* bk = d_in[6];
  const void* Wv = d_in[7]; const void* bv = d_in[8];
  const void* Wp = d_in[9]; const void* bp = d_in[10];
  float* out = (float*)d_out;                  // f32 output; also the xn buffer

  // ---- workspace layout (16B-aligned offsets) ----
  char* ws = (char*)d_ws;
  float* sums  = (float*)(ws);                 // 16 KB
  float* sumsq = (float*)(ws + 16384);         // 16 KB
  float* scale = (float*)(ws + 32768);         // 16 KB
  float* shift = (float*)(ws + 49152);         // 16 KB
  u16* bqkv    = (u16*)(ws + 98304);           // 3 KB  [bq|bk|bvp]
  u16* bpc     = (u16*)(ws + 102400);          // 1 KB
  int* flag    = (int*)(ws + 110592);          // 4 B
  u16* WqkvT   = (u16*)(ws + 114688);          // [WqT|WkT|WvpT] 1536x512 = 1.5 MB
  u16* WpT     = WqkvT + 786432;               // 512x512  = 0.5 MB
  u16* qkv     = WpT + 262144;                 // 4096x1024 bf16 (q|k) = 8 MB
  u16* vWpT    = qkv + 4194304;                // (v@Wp)^T 512x4096 = 4 MB
  u16* Sb      = vWpT + 2097152;               // RC x 4096 bf16
  const size_t S_off = 14794752;               // byte offset of Sb

  // largest score-chunk rows fitting ws (RC=4096 -> 46.3 MB total)
  int RC = 4096;
  while (RC > 128 && S_off + (size_t)RC * 8192 > ws_size) RC >>= 1;

  // 0) dtype probe
  detect_k<<<1, 64, 0, stream>>>((const u16*)x, flag);

  // 1) instance norm -> f32 xn lives in d_out
  hipMemsetAsync(sums, 0, 32768, stream);      // sums + sumsq
  norm_partial<<<dim3(64, 8), 256, 0, stream>>>(x, flag, sums, sumsq);
  norm_finalize<<<16, 256, 0, stream>>>(sums, sumsq, gamma, beta, flag, scale, shift);
  normalize_k<<<8192, 256, 0, stream>>>(x, flag, scale, shift, out);

  // 2) weight/bias prep
  prep_bias_k<<<8, 256, 0, stream>>>(bq, bk, bv, bp, flag, bqkv, bpc);
  bvp_k<<<8, 256, 0, stream>>>(bv, Wp, flag, bqkv);   // overwrite bqkv[1024..]
  wtrans_k<<<dim3(16, 16), 256, 0, stream>>>(Wq, WqkvT,          flag);
  wtrans_k<<<dim3(16, 16), 256, 0, stream>>>(Wk, WqkvT + 262144, flag);
  wtrans_k<<<dim3(16, 16), 256, 0, stream>>>(Wp, WpT,            flag);
  // Wvp = Wv@Wp folded into QKV weights (one-time, deep-pipe all-bf16 GEMM)
  wconv_k<<<128, 256, 0, stream>>>(Wv, vWpT, flag);
  gemm_bt64d<0><<<dim3(4, 8), 512, 0, stream>>>(WpT, 512, vWpT, 512,
      nullptr, nullptr, WqkvT + 524288, 512, 512, 512, 512, 1.f);

  const float sscale = 0.0441941738241592f;    // 512^-0.5

  for (int b = 0; b < BDIM; ++b) {
    float* xnb = out + (size_t)b * SC;
    // fused QKVW: (4096x512 f32) @ (512x1536 bf16) -> q|k to qkv (ld 1024),
    // vWp block transposed straight into vWpT. 768 blocks, 8 waves.
    gemm_bt64<1, 0><<<dim3(12, 64), 512, 0, stream>>>(xnb, 512, WqkvT, 512, bqkv,
        nullptr, qkv, 1024, 4096, 1536, 512, 1.f, vWpT);

    for (int rc = 0; rc < SDIM; rc += RC) {
      // scores chunk: q rows rc.. @ k^T (RC x 4096, K=512) -> Sb bf16
      // R16: 128x256 acc[4][4] deep pipe, grid (16, RC/128) = 512 blocks
      gemm_bt256d<0><<<dim3(16, RC / 128), 512, 0, stream>>>(qkv + (size_t)rc * 1024, 1024,
          qkv + 512, 1024, nullptr, nullptr, Sb, 4096, RC, 4096, 512, sscale);
      softmax_k<<<RC, 256, 0, stream>>>(Sb);
      // out rows rc.. = P @ (v@Wp) + bp + xn   (RC x 512, K=4096, f32 in-place)
      gemm_bt64d<1><<<dim3(4, RC / 64), 512, 0, stream>>>(Sb, 4096, vWpT, 4096, bpc,
          xnb + (size_t)rc * 512, xnb + (size_t)rc * 512, 512, RC, 512, 4096, 1.f);
    }
  }

  (void)in_sizes; (void)n_in; (void)out_size;
}